// Round 1
// baseline (597.855 us; speedup 1.0000x reference)
//
#include <hip/hip_runtime.h>

// VQ-VAE vector-quantize, fused: distances + argmin + gather + loss.
// x: [65536, 256] fp32, dict: [256, 1024] fp32.
// out: q_ste [65536*256] fp32, then loss scalar at out[65536*256].
//
// NUMERICS (bit-exact vs np reference, verified absmax 0.0 R2-R5 — DO NOT CHANGE):
//  - row norm ||f||^2: np pairwise tree (two 128-halves, 8 accumulators,
//    unfused squares, fixed combine tree; 0+sq == sq so zero-init is exact)
//  - enorm ||e||^2: sequential d ascending, unfused square then plain add
//  - dist = fl( fl(A + B) - 2*s ), argmin first-index on exact ties
//  - STE out = fl(x + fl(q - x)); loss on pure q, (1+BETA)/(N*D) scale
//
// PERF (R5 -> R6):
//  - Phase N deleted: row-norm chain piggybacked onto main-loop steps 0..15
//    (same chunk order => identical summation chain). Dist-finalize for ct
//    moved to the top of step (ct+1)*16, after the barrier that publishes
//    rnormS. Saves 16 latency-serialized stage rounds + 32 barriers + one
//    full 64 MB global x pass.
//  - STAGE_FX split (T14): global loads issued at step top (regs live across
//    compute), ds_write sunk below the dd-loop via sched_barrier(0). x HBM/L3
//    latency hides under ~4096 cyc of fma issue instead of serializing.
//  - Epilogue: unroll 2 for load ILP (lsum chain order preserved);
//    nontemporal stores for write-only out (kill L2 RFO fetch).

#define NROWS 65536
#define DDIM  256
#define KC    1024
#define BM    128            // rows per block
#define BC    256            // codes per ct tile
#define DC    16             // d-chunk per pipeline step
#define NDC   16             // DDIM/DC
#define NCT   4              // KC/BC
#define NSTEP 64             // NCT*NDC
#define FXW   160            // 32 row-groups * pitch 5 (160%32==0 -> clean banks)

#define GLOAD_LDS16(gp, lp) __builtin_amdgcn_global_load_lds( \
    (const __attribute__((address_space(1))) void*)(gp),      \
    (__attribute__((address_space(3))) void*)(lp), 16, 0, 0)

// x chunk [128 rows][16 d] prefetch: loads issued early into pv0/pv1 (live
// across the step's compute), LDS write sunk to just before the barrier.
#define STAGE_FX_LOAD(dc_) do {                                                 \
    const int r0_ = tid >> 2, c0_ = tid & 3;                                    \
    pv0 = *(const float4*)&x[(size_t)(rowbase + r0_) * DDIM + (dc_) * DC + c0_ * 4];      \
    pv1 = *(const float4*)&x[(size_t)(rowbase + 64 + r0_) * DDIM + (dc_) * DC + c0_ * 4]; \
} while (0)

#define STAGE_FX_WRITE(dstbuf) do {                                             \
    const int r0_ = tid >> 2, c0_ = tid & 3;                                    \
    float* b0_ = (dstbuf) + (c0_ * 4) * FXW + (r0_ >> 2) * 5 + (r0_ & 3);       \
    b0_[0 * FXW] = pv0.x; b0_[1 * FXW] = pv0.y;                                 \
    b0_[2 * FXW] = pv0.z; b0_[3 * FXW] = pv0.w;                                 \
    float* b1_ = b0_ + 16 * 5; /* +64 rows = +16 groups */                      \
    b1_[0 * FXW] = pv1.x; b1_[1 * FXW] = pv1.y;                                 \
    b1_[2 * FXW] = pv1.z; b1_[3 * FXW] = pv1.w;                                 \
} while (0)

// dict tile [16 d][256 codes] via async DMA: lds dest = uniform + lane*16.
#define STAGE_DICT(pbuf, ct_, dc_) do {                                         \
    _Pragma("unroll")                                                           \
    for (int i_ = 0; i_ < 4; ++i_) {                                            \
        int flat_ = i_ * 256 + tid;                                             \
        int dd_ = flat_ >> 6;            /* wave-uniform */                     \
        int l4_ = (flat_ & 63) * 4;      /* lane*4 floats = lane*16 B */        \
        GLOAD_LDS16(&dict[(size_t)((dc_) * DC + dd_) * KC + (ct_) * BC + l4_],  \
                    (pbuf) + dd_ * BC + l4_);                                   \
    }                                                                           \
} while (0)

// Pre-kernel: codebook column norms (np order: rounded square then plain add,
// sequential d ascending) + transposed codebook + loss zero-init.
__global__ __launch_bounds__(256) void vq_prep(const float* __restrict__ dict,
                                               float* __restrict__ enorm,
                                               float* __restrict__ dictT,
                                               float* __restrict__ loss) {
#pragma clang fp contract(off)
    int k = blockIdx.x * 256 + threadIdx.x;
    if (k == 0) *loss = 0.f;   // runs before vq_main (stream order)
    float s = 0.f;
    #pragma unroll 8
    for (int d = 0; d < DDIM; ++d) {
        float v = dict[(size_t)d * KC + k];
        float sq = v * v;          // rounded square (np temp array)
        s = s + sq;                // plain add, NOT fma (chain stays sequential)
        dictT[(size_t)k * DDIM + d] = v;
    }
    enorm[k] = s;
}

__global__ __launch_bounds__(256, 2) void vq_main(const float* __restrict__ x,
                                                  const float* __restrict__ dict,
                                                  const float* __restrict__ enorm,
                                                  const float* __restrict__ dictT,
                                                  float* __restrict__ out,
                                                  float* __restrict__ loss) {
    __shared__ float fXb[2][DC * FXW];   // 10 KB each
    __shared__ float dTs[2][DC * BC];    // 16 KB each
    __shared__ float rnormS[BM];         // total ~53 KB -> 2 blocks/CU

    const int tid = threadIdx.x;
    const int tx  = tid & 15;            // 16 code-groups x 16 codes = 256
    const int ty  = tid >> 4;            // 16 row-groups  x  8 rows  = 128
    const int rowbase = blockIdx.x * BM;

    float4 pv0, pv1;                     // x prefetch regs (live across compute)

    // ---- Prologue: dict tile (0,0) DMA + x chunk 0 staged synchronously.
    STAGE_DICT(&dTs[0][0], 0, 0);
    STAGE_FX_LOAD(0);
    STAGE_FX_WRITE(&fXb[0][0]);
    __syncthreads();

    // Row-norm state (np pairwise tree), accumulated during steps 0..15.
    float r8[8] = {0.f, 0.f, 0.f, 0.f, 0.f, 0.f, 0.f, 0.f};
    float halfv0 = 0.f;

    float Arow[8];
    float minv[8];
    int   mini[8];
    #pragma unroll
    for (int r = 0; r < 8; ++r) { minv[r] = 3.4e38f; mini[r] = 0; }

    float acc[8][16];

    // ---- Main: 64 steps, one barrier each.
    #pragma unroll 2                     // compile-time buffer parity
    for (int s = 0; s < NSTEP; ++s) {
        const int p = s & 1;
        if (s < NSTEP - 1) {
            const int ns = s + 1;
            STAGE_DICT(&dTs[1 - p][0], ns >> 4, ns & 15);  // async, 0 regs
            STAGE_FX_LOAD(ns & 15);                        // issue early
        }
        if ((s & 15) == 0) {
            if (s != 0) {
                // dist-finalize for ct = (s>>4)-1, using acc from the previous
                // 16 steps. Runs after the barrier that published rnormS (s==16).
                if (s == 16) {
                    #pragma unroll
                    for (int r = 0; r < 8; ++r) Arow[r] = rnormS[ty * 8 + r];
                }
                // dist = fl( fl(A + B) - 2*s ) — np rounding chain (fma of
                // t1 - 2*acc bit-identical: 2*acc exact). Codes ascend with
                // (ct, j) for fixed tx -> strict < keeps FIRST min index.
                const int cbase = ((s >> 4) - 1) * BC;
                float en[16];
                #pragma unroll
                for (int j = 0; j < 16; ++j)
                    en[j] = enorm[cbase + (j >> 2) * 64 + tx * 4 + (j & 3)];
                #pragma unroll
                for (int r = 0; r < 8; ++r)
                    #pragma unroll
                    for (int j = 0; j < 16; ++j) {
                        int code = cbase + (j >> 2) * 64 + tx * 4 + (j & 3);
                        float t1 = Arow[r] + en[j];
                        float dist = t1 - 2.0f * acc[r][j];
                        if (dist < minv[r]) { minv[r] = dist; mini[r] = code; }
                    }
            }
            #pragma unroll
            for (int r = 0; r < 8; ++r)
                #pragma unroll
                for (int j = 0; j < 16; ++j) acc[r][j] = 0.f;
        }
        // Row-norm piggyback on ct=0 pass: chunk s is resident in fXb[p] for
        // s<16, exactly phase-N's chunk order -> identical summation chain.
        if (s < NDC && tid < BM) {
#pragma clang fp contract(off)
            #pragma unroll
            for (int dd = 0; dd < DC; ++dd) {   // elem e=s*16+dd; e%8 == dd%8
                float v  = fXb[p][dd * FXW + (tid >> 2) * 5 + (tid & 3)];
                float sq = v * v;
                r8[dd & 7] = r8[dd & 7] + sq;
            }
            if (s == 7) {                       // half boundary at elem 128
                halfv0 = ((r8[0] + r8[1]) + (r8[2] + r8[3]))
                       + ((r8[4] + r8[5]) + (r8[6] + r8[7]));
                #pragma unroll
                for (int j = 0; j < 8; ++j) r8[j] = 0.f;
            }
            if (s == NDC - 1) {
                float h1 = ((r8[0] + r8[1]) + (r8[2] + r8[3]))
                         + ((r8[4] + r8[5]) + (r8[6] + r8[7]));
                rnormS[tid] = halfv0 + h1;
            }
        }
        #pragma unroll 4
        for (int dd = 0; dd < DC; ++dd) {
            const float4 f0 = *(const float4*)&fXb[p][dd * FXW + (ty * 2) * 5];
            const float4 f1 = *(const float4*)&fXb[p][dd * FXW + (ty * 2 + 1) * 5];
            const float4 e0 = *(const float4*)&dTs[p][dd * BC + tx * 4];
            const float4 e1 = *(const float4*)&dTs[p][dd * BC + 64 + tx * 4];
            const float4 e2 = *(const float4*)&dTs[p][dd * BC + 128 + tx * 4];
            const float4 e3 = *(const float4*)&dTs[p][dd * BC + 192 + tx * 4];
            const float fr[8]  = {f0.x, f0.y, f0.z, f0.w, f1.x, f1.y, f1.z, f1.w};
            const float ec[16] = {e0.x, e0.y, e0.z, e0.w, e1.x, e1.y, e1.z, e1.w,
                                  e2.x, e2.y, e2.z, e2.w, e3.x, e3.y, e3.z, e3.w};
            #pragma unroll
            for (int r = 0; r < 8; ++r)
                #pragma unroll
                for (int j = 0; j < 16; ++j)
                    acc[r][j] = fmaf(fr[r], ec[j], acc[r][j]);
        }
        // Pin the x LDS write BELOW the compute so the x-load latency hides
        // under the fma issue instead of stalling the step's front.
        __builtin_amdgcn_sched_barrier(0);
        if (s < NSTEP - 1) STAGE_FX_WRITE(&fXb[1 - p][0]);
        __syncthreads();
    }

    // Final ct=3 finalize (acc holds steps 48..63).
    {
        const int cbase = 3 * BC;
        float en[16];
        #pragma unroll
        for (int j = 0; j < 16; ++j)
            en[j] = enorm[cbase + (j >> 2) * 64 + tx * 4 + (j & 3)];
        #pragma unroll
        for (int r = 0; r < 8; ++r)
            #pragma unroll
            for (int j = 0; j < 16; ++j) {
                int code = cbase + (j >> 2) * 64 + tx * 4 + (j & 3);
                float t1 = Arow[r] + en[j];
                float dist = t1 - 2.0f * acc[r][j];
                if (dist < minv[r]) { minv[r] = dist; mini[r] = code; }
            }
    }

    // Cross-lane argmin over the 16 tx lanes (xor<16 stays in-wave; lane =
    // (ty&3)*16 + tx). Tie -> smaller index (first occurrence).
    #pragma unroll
    for (int m = 1; m < 16; m <<= 1)
        #pragma unroll
        for (int r = 0; r < 8; ++r) {
            float ov = __shfl_xor(minv[r], m, 64);
            int   oi = __shfl_xor(mini[r], m, 64);
            if (ov < minv[r] || (ov == minv[r] && oi < mini[r])) {
                minv[r] = ov; mini[r] = oi;
            }
        }

    int* idx_s = (int*)&dTs[0][0];       // loop-end barrier covers last compute
    if (tx == 0) {
        #pragma unroll
        for (int r = 0; r < 8; ++r) idx_s[ty * 8 + r] = mini[r];
    }
    __syncthreads();

    // Epilogue: gather codebook row (dictT L2-resident), re-read x (L3-hot),
    // emulate STE out = fl(x + fl(q-x)), loss on pure q (before STE).
    // unroll 2 = load ILP; lsum add chain order preserved (no reassociation).
    // Nontemporal store: out is write-only, skip L2 RFO.
    float lsum = 0.f;
    {
#pragma clang fp contract(off)
        #pragma unroll 2
        for (int i = 0; i < BM; ++i) {
            int k = idx_s[i];
            float qv = dictT[(size_t)k * DDIM + tid];
            float xv = x[(size_t)(rowbase + i) * DDIM + tid];
            float diff = qv - xv;                                 // fl(q - x)
            __builtin_nontemporal_store(xv + diff,
                &out[(size_t)(rowbase + i) * DDIM + tid]);        // fl(x + fl(q-x))
            float d = xv - qv;
            float dsq = d * d;
            lsum = lsum + dsq;
        }
    }
    #pragma unroll
    for (int off = 32; off > 0; off >>= 1)
        lsum += __shfl_down(lsum, off, 64);
    if ((tid & 63) == 0)
        atomicAdd(loss, lsum * (1.25f / 16777216.0f));  // (1+BETA)/(N*D)
}

extern "C" void kernel_launch(void* const* d_in, const int* in_sizes, int n_in,
                              void* d_out, int out_size, void* d_ws, size_t ws_size,
                              hipStream_t stream) {
    (void)in_sizes; (void)n_in; (void)out_size; (void)ws_size;
    const float* x    = (const float*)d_in[0];
    const float* dict = (const float*)d_in[1];
    float* out   = (float*)d_out;
    float* enorm = (float*)d_ws;                 // 1024 floats
    float* dictT = enorm + KC;                   // 1024*256 floats (1 MB)
    float* loss  = out + (size_t)NROWS * DDIM;   // scalar slot after q

    vq_prep<<<KC / 256, 256, 0, stream>>>(dict, enorm, dictT, loss);
    vq_main<<<NROWS / BM, 256, 0, stream>>>(x, dict, enorm, dictT, out, loss);
}

// Round 2
// 535.071 us; speedup vs baseline: 1.1173x; 1.1173x over previous
//
#include <hip/hip_runtime.h>

// VQ-VAE vector-quantize, fused: distances + argmin + gather + loss.
// x: [65536, 256] fp32, dict: [256, 1024] fp32.
// out: q_ste [65536*256] fp32, then loss scalar at out[65536*256].
//
// NUMERICS (bit-exact vs np reference, verified absmax 0.0 R2-R6 — DO NOT CHANGE):
//  - row norm ||f||^2: np pairwise tree (two 128-halves, 8 accumulators r8[e&7],
//    unfused squares, fixed combine tree; 0+sq == sq so zero-init is exact)
//  - enorm ||e||^2: sequential d ascending, unfused square then plain add
//  - dist = fl( fl(A + B) - 2*s ), argmin first-index on exact ties
//  - STE out = fl(x + fl(q - x)); loss on pure q, (1+BETA)/(N*D) scale
//
// PERF (R6 -> R7): R6's in-loop norm piggyback + T14 prefetch regs +
// sched_barrier(0) spilled to scratch (WRITE_SIZE 65.6 -> 243.6 MB). R7 keeps
// the Phase-N deletion but computes row norms in a tiny standalone kernel
// (thread-per-row, exact same summation chain); vq_main reverts to the proven
// R5 loop structure (in-step staging, finalize at (s&15)==15). Epilogue keeps
// nontemporal stores + unroll 2.

#define NROWS 65536
#define DDIM  256
#define KC    1024
#define BM    128            // rows per block
#define BC    256            // codes per ct tile
#define DC    16             // d-chunk per pipeline step
#define NDC   16             // DDIM/DC
#define NCT   4              // KC/BC
#define NSTEP 64             // NCT*NDC
#define FXW   160            // 32 row-groups * pitch 5 (160%32==0 -> clean banks)

#define GLOAD_LDS16(gp, lp) __builtin_amdgcn_global_load_lds( \
    (const __attribute__((address_space(1))) void*)(gp),      \
    (__attribute__((address_space(3))) void*)(lp), 16, 0, 0)

// x chunk [128 rows][16 d] -> LDS transposed [d][row-group*5+r]. 2 float4/thread,
// regs die immediately (stores right after the vmcnt wait).
#define STAGE_FX(dstbuf, dc_) do {                                              \
    const int r0_ = tid >> 2, c0_ = tid & 3;                                    \
    const float4 v0_ = *(const float4*)&x[(size_t)(rowbase + r0_) * DDIM + (dc_) * DC + c0_ * 4];      \
    const float4 v1_ = *(const float4*)&x[(size_t)(rowbase + 64 + r0_) * DDIM + (dc_) * DC + c0_ * 4]; \
    float* b0_ = (dstbuf) + (c0_ * 4) * FXW + (r0_ >> 2) * 5 + (r0_ & 3);       \
    b0_[0 * FXW] = v0_.x; b0_[1 * FXW] = v0_.y;                                 \
    b0_[2 * FXW] = v0_.z; b0_[3 * FXW] = v0_.w;                                 \
    float* b1_ = b0_ + 16 * 5; /* +64 rows = +16 groups */                      \
    b1_[0 * FXW] = v1_.x; b1_[1 * FXW] = v1_.y;                                 \
    b1_[2 * FXW] = v1_.z; b1_[3 * FXW] = v1_.w;                                 \
} while (0)

// dict tile [16 d][256 codes] via async DMA: lds dest = uniform + lane*16.
#define STAGE_DICT(pbuf, ct_, dc_) do {                                         \
    _Pragma("unroll")                                                           \
    for (int i_ = 0; i_ < 4; ++i_) {                                            \
        int flat_ = i_ * 256 + tid;                                             \
        int dd_ = flat_ >> 6;            /* wave-uniform */                     \
        int l4_ = (flat_ & 63) * 4;      /* lane*4 floats = lane*16 B */        \
        GLOAD_LDS16(&dict[(size_t)((dc_) * DC + dd_) * KC + (ct_) * BC + l4_],  \
                    (pbuf) + dd_ * BC + l4_);                                   \
    }                                                                           \
} while (0)

// Pre-kernel: codebook column norms (np order: rounded square then plain add,
// sequential d ascending) + transposed codebook + loss zero-init.
__global__ __launch_bounds__(256) void vq_prep(const float* __restrict__ dict,
                                               float* __restrict__ enorm,
                                               float* __restrict__ dictT,
                                               float* __restrict__ loss) {
#pragma clang fp contract(off)
    int k = blockIdx.x * 256 + threadIdx.x;
    if (k == 0) *loss = 0.f;   // runs before vq_main (stream order)
    float s = 0.f;
    #pragma unroll 8
    for (int d = 0; d < DDIM; ++d) {
        float v = dict[(size_t)d * KC + k];
        float sq = v * v;          // rounded square (np temp array)
        s = s + sq;                // plain add, NOT fma (chain stays sequential)
        dictT[(size_t)k * DDIM + d] = v;
    }
    enorm[k] = s;
}

// Row norms ||f||^2, thread-per-row, bit-exact np pairwise chain:
// elements d ascending; accumulator index d&7 (float4 at d=4c+k -> (c&1)*4+k);
// halves combined at d=127 / d=255 with the fixed tree. L1 absorbs the 1 KB
// lane stride (each 64B line consumed by the same thread across 4 iters).
__global__ __launch_bounds__(256) void vq_rnorm(const float* __restrict__ x,
                                                float* __restrict__ rnorm) {
#pragma clang fp contract(off)
    int row = blockIdx.x * 256 + threadIdx.x;
    const float* xr = x + (size_t)row * DDIM;
    float r8[8] = {0.f, 0.f, 0.f, 0.f, 0.f, 0.f, 0.f, 0.f};
    float halfv0 = 0.f;
    #pragma unroll 8
    for (int c = 0; c < 64; ++c) {       // d = 4c..4c+3
        float4 v = *(const float4*)&xr[c * 4];
        int b = (c & 1) * 4;             // (4c+k)&7 == b+k
        float s0 = v.x * v.x; r8[b + 0] = r8[b + 0] + s0;
        float s1 = v.y * v.y; r8[b + 1] = r8[b + 1] + s1;
        float s2 = v.z * v.z; r8[b + 2] = r8[b + 2] + s2;
        float s3 = v.w * v.w; r8[b + 3] = r8[b + 3] + s3;
        if (c == 31) {                   // half boundary at elem 128
            halfv0 = ((r8[0] + r8[1]) + (r8[2] + r8[3]))
                   + ((r8[4] + r8[5]) + (r8[6] + r8[7]));
            #pragma unroll
            for (int j = 0; j < 8; ++j) r8[j] = 0.f;
        }
    }
    float h1 = ((r8[0] + r8[1]) + (r8[2] + r8[3]))
             + ((r8[4] + r8[5]) + (r8[6] + r8[7]));
    rnorm[row] = halfv0 + h1;
}

__global__ __launch_bounds__(256, 2) void vq_main(const float* __restrict__ x,
                                                  const float* __restrict__ dict,
                                                  const float* __restrict__ enorm,
                                                  const float* __restrict__ dictT,
                                                  const float* __restrict__ rnorm,
                                                  float* __restrict__ out,
                                                  float* __restrict__ loss) {
    __shared__ float fXb[2][DC * FXW];   // 10 KB each
    __shared__ float dTs[2][DC * BC];    // 16 KB each  -> total 52 KB, 2 blk/CU

    const int tid = threadIdx.x;
    const int tx  = tid & 15;            // 16 code-groups x 16 codes = 256
    const int ty  = tid >> 4;            // 16 row-groups  x  8 rows  = 128
    const int rowbase = blockIdx.x * BM;

    // Row norms from the standalone kernel (broadcast loads: 16 lanes share ty).
    float Arow[8];
    #pragma unroll
    for (int r = 0; r < 8; ++r) Arow[r] = rnorm[rowbase + ty * 8 + r];

    float minv[8];
    int   mini[8];
    #pragma unroll
    for (int r = 0; r < 8; ++r) { minv[r] = 3.4e38f; mini[r] = 0; }

    // ---- Prologue: dict tile (0,0) DMA + x chunk 0, one barrier drains both.
    STAGE_DICT(&dTs[0][0], 0, 0);
    STAGE_FX(&fXb[0][0], 0);
    __syncthreads();

    float acc[8][16];
    // ---- Main: 64 steps, one barrier each.
    #pragma unroll 2                     // compile-time buffer parity
    for (int s = 0; s < NSTEP; ++s) {
        const int p = s & 1;
        if (s < NSTEP - 1) {
            const int ns = s + 1;
            STAGE_DICT(&dTs[1 - p][0], ns >> 4, ns & 15);  // async, 0 regs
            STAGE_FX(&fXb[1 - p][0], ns & 15);             // regs die here
        }
        if ((s & 15) == 0) {
            #pragma unroll
            for (int r = 0; r < 8; ++r)
                #pragma unroll
                for (int j = 0; j < 16; ++j) acc[r][j] = 0.f;
        }
        #pragma unroll 4
        for (int dd = 0; dd < DC; ++dd) {
            const float4 f0 = *(const float4*)&fXb[p][dd * FXW + (ty * 2) * 5];
            const float4 f1 = *(const float4*)&fXb[p][dd * FXW + (ty * 2 + 1) * 5];
            const float4 e0 = *(const float4*)&dTs[p][dd * BC + tx * 4];
            const float4 e1 = *(const float4*)&dTs[p][dd * BC + 64 + tx * 4];
            const float4 e2 = *(const float4*)&dTs[p][dd * BC + 128 + tx * 4];
            const float4 e3 = *(const float4*)&dTs[p][dd * BC + 192 + tx * 4];
            const float fr[8]  = {f0.x, f0.y, f0.z, f0.w, f1.x, f1.y, f1.z, f1.w};
            const float ec[16] = {e0.x, e0.y, e0.z, e0.w, e1.x, e1.y, e1.z, e1.w,
                                  e2.x, e2.y, e2.z, e2.w, e3.x, e3.y, e3.z, e3.w};
            #pragma unroll
            for (int r = 0; r < 8; ++r)
                #pragma unroll
                for (int j = 0; j < 16; ++j)
                    acc[r][j] = fmaf(fr[r], ec[j], acc[r][j]);
        }
        if ((s & 15) == 15) {
            // dist = fl( fl(A + B) - 2*s ) — np rounding chain (fma of
            // t1 - 2*acc bit-identical: 2*acc exact). Codes ascend with
            // (ct, j) for fixed tx -> strict < keeps FIRST min index.
            const int cbase = (s >> 4) * BC;
            float en[16];
            #pragma unroll
            for (int j = 0; j < 16; ++j)
                en[j] = enorm[cbase + (j >> 2) * 64 + tx * 4 + (j & 3)];
            #pragma unroll
            for (int r = 0; r < 8; ++r)
                #pragma unroll
                for (int j = 0; j < 16; ++j) {
                    int code = cbase + (j >> 2) * 64 + tx * 4 + (j & 3);
                    float t1 = Arow[r] + en[j];
                    float dist = t1 - 2.0f * acc[r][j];
                    if (dist < minv[r]) { minv[r] = dist; mini[r] = code; }
                }
        }
        __syncthreads();
    }

    // Cross-lane argmin over the 16 tx lanes (xor<16 stays in-wave; lane =
    // (ty&3)*16 + tx). Tie -> smaller index (first occurrence).
    #pragma unroll
    for (int m = 1; m < 16; m <<= 1)
        #pragma unroll
        for (int r = 0; r < 8; ++r) {
            float ov = __shfl_xor(minv[r], m, 64);
            int   oi = __shfl_xor(mini[r], m, 64);
            if (ov < minv[r] || (ov == minv[r] && oi < mini[r])) {
                minv[r] = ov; mini[r] = oi;
            }
        }

    int* idx_s = (int*)&dTs[0][0];       // loop-end barrier covers last compute
    if (tx == 0) {
        #pragma unroll
        for (int r = 0; r < 8; ++r) idx_s[ty * 8 + r] = mini[r];
    }
    __syncthreads();

    // Epilogue: gather codebook row (dictT L2-resident), re-read x (L3-hot),
    // emulate STE out = fl(x + fl(q-x)), loss on pure q (before STE).
    // unroll 2 = load ILP; lsum add chain order preserved (no reassociation).
    // Nontemporal store: out is write-only, skip L2 RFO.
    float lsum = 0.f;
    {
#pragma clang fp contract(off)
        #pragma unroll 2
        for (int i = 0; i < BM; ++i) {
            int k = idx_s[i];
            float qv = dictT[(size_t)k * DDIM + tid];
            float xv = x[(size_t)(rowbase + i) * DDIM + tid];
            float diff = qv - xv;                                 // fl(q - x)
            __builtin_nontemporal_store(xv + diff,
                &out[(size_t)(rowbase + i) * DDIM + tid]);        // fl(x + fl(q-x))
            float d = xv - qv;
            float dsq = d * d;
            lsum = lsum + dsq;
        }
    }
    #pragma unroll
    for (int off = 32; off > 0; off >>= 1)
        lsum += __shfl_down(lsum, off, 64);
    if ((tid & 63) == 0)
        atomicAdd(loss, lsum * (1.25f / 16777216.0f));  // (1+BETA)/(N*D)
}

extern "C" void kernel_launch(void* const* d_in, const int* in_sizes, int n_in,
                              void* d_out, int out_size, void* d_ws, size_t ws_size,
                              hipStream_t stream) {
    (void)in_sizes; (void)n_in; (void)out_size; (void)ws_size;
    const float* x    = (const float*)d_in[0];
    const float* dict = (const float*)d_in[1];
    float* out   = (float*)d_out;
    float* enorm = (float*)d_ws;                 // 1024 floats
    float* dictT = enorm + KC;                   // 1024*256 floats (1 MB)
    float* rnorm = dictT + (size_t)KC * DDIM;    // 65536 floats (256 KB)
    float* loss  = out + (size_t)NROWS * DDIM;   // scalar slot after q

    vq_prep<<<KC / 256, 256, 0, stream>>>(dict, enorm, dictT, loss);
    vq_rnorm<<<NROWS / 256, 256, 0, stream>>>(x, rnorm);
    vq_main<<<NROWS / BM, 256, 0, stream>>>(x, dict, enorm, dictT, rnorm, out, loss);
}